// Round 5
// baseline (92.812 us; speedup 1.0000x reference)
//
#include <hip/hip_runtime.h>

// Problem constants (from reference setup_inputs)
constexpr int B = 8, C = 3, H = 544, W = 960;
constexpr int KH = 3, KW = 3;
constexpr int HW = H * W;        // 522240
constexpr int WT = 4;            // outputs per thread along W
constexpr int HT = 4;            // output rows per thread
constexpr int WQ = W / WT;       // 240
constexpr int HG = H / HT;       // 136
constexpr int NK = C * KH * KW;  // 27 filter planes
constexpr int BLOCK = 256;
constexpr int TOTAL = B * HG * WQ;   // 261120 threads
constexpr int NBLK = TOTAL / BLOCK;  // 1020 blocks
static_assert(TOTAL % BLOCK == 0, "grid must be exact");

typedef float f32x4 __attribute__((ext_vector_type(4)));

__device__ __forceinline__ void load_row(const float* xr, bool valid,
                                         bool left, bool right,
                                         float xv[WT + 2]) {
    if (valid) {
        f32x4 m = *reinterpret_cast<const f32x4*>(xr);
        xv[1] = m[0]; xv[2] = m[1]; xv[3] = m[2]; xv[4] = m[3];
        xv[0] = left  ? xr[-1] : 0.f;
        xv[5] = right ? xr[WT] : 0.f;
    } else {
        #pragma unroll
        for (int q = 0; q < WT + 2; ++q) xv[q] = 0.f;
    }
}

__global__ __launch_bounds__(BLOCK) void DynFilter_kernel(
    const float* __restrict__ x,     // [B, C, H, W]
    const float* __restrict__ filt,  // [B, 27, H, W]
    float* __restrict__ out)         // [B, 1, H, W]
{
    int tid = (int)blockIdx.x * BLOCK + (int)threadIdx.x;

    int wq = tid % WQ;
    int t  = tid / WQ;
    int hg = t % HG;
    int b  = t / HG;
    int h0 = hg * HT;          // rows h0 .. h0+3 computed by this thread
    int w0 = wq * WT;
    bool left  = (w0 > 0);
    bool right = (w0 + WT < W);

    f32x4 a0 = {0,0,0,0}, a1 = {0,0,0,0}, a2 = {0,0,0,0}, a3 = {0,0,0,0};

    const float* fbase = filt + (size_t)b * NK * HW + (size_t)h0 * W + w0;

    #pragma unroll
    for (int c = 0; c < C; ++c) {
        const float* xc = x + ((size_t)b * C + c) * HW;

        // rolling x window: image rows h0-1 .. h0+4 (6 rows), cols w0-1 .. w0+4
        float xw[HT + 2][WT + 2];
        load_row(xc + (size_t)(h0 - 1) * W + w0, h0 > 0,     left, right, xw[0]);
        #pragma unroll
        for (int rr = 1; rr <= 4; ++rr)   // rows h0 .. h0+3 always valid
            load_row(xc + (size_t)(h0 - 1 + rr) * W + w0, true, left, right, xw[rr]);
        load_row(xc + (size_t)(h0 + 4) * W + w0, h0 + 4 < H, left, right, xw[5]);

        #pragma unroll
        for (int i = 0; i < KH; ++i) {
            #pragma unroll
            for (int j = 0; j < KW; ++j) {
                int k = c * (KH * KW) + i * KW + j;
                const float* fp = fbase + (size_t)k * HW;
                f32x4 g0 = *reinterpret_cast<const f32x4*>(fp);
                f32x4 g1 = *reinterpret_cast<const f32x4*>(fp + W);
                f32x4 g2 = *reinterpret_cast<const f32x4*>(fp + 2 * W);
                f32x4 g3 = *reinterpret_cast<const f32x4*>(fp + 3 * W);
                #pragma unroll
                for (int q = 0; q < 4; ++q) {
                    a0[q] += xw[i    ][j + q] * g0[q];
                    a1[q] += xw[i + 1][j + q] * g1[q];
                    a2[q] += xw[i + 2][j + q] * g2[q];
                    a3[q] += xw[i + 3][j + q] * g3[q];
                }
            }
        }
    }

    float* op = out + (size_t)b * HW + (size_t)h0 * W + w0;
    __builtin_nontemporal_store(a0, reinterpret_cast<f32x4*>(op));
    __builtin_nontemporal_store(a1, reinterpret_cast<f32x4*>(op + W));
    __builtin_nontemporal_store(a2, reinterpret_cast<f32x4*>(op + 2 * W));
    __builtin_nontemporal_store(a3, reinterpret_cast<f32x4*>(op + 3 * W));
}

extern "C" void kernel_launch(void* const* d_in, const int* in_sizes, int n_in,
                              void* d_out, int out_size, void* d_ws, size_t ws_size,
                              hipStream_t stream) {
    const float* x    = (const float*)d_in[0];
    const float* filt = (const float*)d_in[1];
    float* out        = (float*)d_out;

    DynFilter_kernel<<<NBLK, BLOCK, 0, stream>>>(x, filt, out);
}